// Round 15
// baseline (50.356 us; speedup 1.0000x reference)
//
#include <hip/hip_runtime.h>

typedef __bf16 bf16x8 __attribute__((ext_vector_type(8)));
typedef __bf16 bf16x4 __attribute__((ext_vector_type(4)));
typedef float f32x4 __attribute__((ext_vector_type(4)));
typedef float f32x16 __attribute__((ext_vector_type(16)));
typedef unsigned short u16x8 __attribute__((ext_vector_type(8)));

#define MFMA16(a, b, c) __builtin_amdgcn_mfma_f32_16x16x32_bf16((a), (b), (c), 0, 0, 0)
#define MFMA32(a, b, c) __builtin_amdgcn_mfma_f32_32x32x16_bf16((a), (b), (c), 0, 0, 0)

#define SCALE_Q 0.180336880f  // 0.125 * log2(e): scores land in log2 domain
#define DEFER_TH 11.5415603f  // 8 * log2(e)

// fast exp2 on gfx950 (v_exp_f32 is base-2 natively)
static __device__ __forceinline__ float fexp2(float x) {
  return __builtin_amdgcn_exp2f(x);
}

// fp32 -> bf16 bits, round-to-nearest-even
static __device__ __forceinline__ unsigned short f2bf(float f) {
  unsigned int u = __float_as_uint(f);
  u += 0x7fffu + ((u >> 16) & 1u);
  return (unsigned short)(u >> 16);
}
static __device__ __forceinline__ float bf2f(unsigned short s) {
  return __uint_as_float((unsigned int)s << 16);
}
// packed f32x2 -> bf16x2 (RNE), single VALU op
static __device__ __forceinline__ unsigned int cvtpk(float lo, float hi) {
  unsigned int r;
  asm("v_cvt_pk_bf16_f32 %0, %1, %2" : "=v"(r) : "v"(lo), "v"(hi));
  return r;
}
static __device__ __forceinline__ void plswap(unsigned int& a, unsigned int& b) {
  asm("v_permlane32_swap_b32 %0, %1" : "+v"(a), "+v"(b));
}

// async global->LDS, 16B per lane
static __device__ __forceinline__ void gld_lds16(const void* g, void* l) {
  __builtin_amdgcn_global_load_lds(
      (const __attribute__((address_space(1))) unsigned int*)(g),
      (__attribute__((address_space(3))) unsigned int*)(l), 16, 0, 0);
}

// ---------------------------------------------------------------------------
// Kernel 0: blocks 0..191: W [1024][64] fp32 x3 -> Wt bf16 [192][1024],
// pre-swizzled in 16B chunks (chunk j stored at j^(n&7)); Wq part * SCALE_Q
// (log2-domain scores). Blocks 192..319: mask -> mAddG float (0 / -inf).
// ---------------------------------------------------------------------------
__global__ __launch_bounds__(128) void wt_kernel(
    const float* __restrict__ Wq, const float* __restrict__ Wk,
    const float* __restrict__ Wv, unsigned short* __restrict__ Wt,
    const int* __restrict__ mask, float* __restrict__ mAddG) {
  const int bid = blockIdx.x;
  if (bid >= 192) {
    const int idx = (bid - 192) * 128 + threadIdx.x;  // 0..16383
    mAddG[idx] = mask[idx] ? 0.0f : -__builtin_inff();
    return;
  }
  const int n = bid;           // 0..191 (qkv output col)
  const int jl = threadIdx.x;  // logical 8-elem chunk of K
  const float* W;
  int col;
  float scale;
  if (n < 64)       { W = Wq; col = n;       scale = SCALE_Q; }
  else if (n < 128) { W = Wk; col = n - 64;  scale = 1.0f; }
  else              { W = Wv; col = n - 128; scale = 1.0f; }
  const int js = (jl & ~7) | ((jl & 7) ^ (n & 7));  // swizzled chunk position
  u16x8 o;
#pragma unroll
  for (int e = 0; e < 8; ++e) o[e] = f2bf(W[(jl * 8 + e) * 64 + col] * scale);
  *reinterpret_cast<u16x8*>(&Wt[n * 1024 + js * 8]) = o;
}

// ---------------------------------------------------------------------------
// Kernel 1: QKV projection GEMM, 64-ROW TILE. M=16384, K=1024, N=192.
// Tile 64x192, grid 256, 512 threads (8 waves: 2 row-groups x 4 col-groups).
// Each wave computes TWO 16-row subtiles with the SAME 6 B-fragments:
// per step 4 A-reads + 6 B-reads feed 12 MFMA16 (reads/MFMA 0.83 vs 1.67).
// W double-buffered via global_load_lds; x reg pair 2-deep with raw
// s_barrier + counted vmcnt(2). LDS 85 KB -> 1 block/CU.
// ---------------------------------------------------------------------------
__global__ __launch_bounds__(512, 2) void qkv_kernel(
    const float* __restrict__ x, const unsigned short* __restrict__ Wt,
    const float* __restrict__ bq, const float* __restrict__ bk,
    const float* __restrict__ bv, unsigned short* __restrict__ Q,
    unsigned short* __restrict__ K, unsigned short* __restrict__ Vt) {
  __shared__ __align__(16) unsigned short xs[2][64][72];    // 36.9 KB padded
  __shared__ __align__(16) unsigned short ws[2][192 * 64];  // 48 KB swizzled
  const int tid = threadIdx.x;
  const int w = tid >> 6, lane = tid & 63;
  const int lr = lane & 15, lg = lane >> 4;
  const int wg = w >> 2, wc = w & 3;
  const int m0 = blockIdx.x * 64;

  // x staging: thread covers slot tid (row 0..31) and slot 512+tid (row+32)
  const int xrow = tid >> 4, xc4 = (tid & 15) * 4;
  const float* xsrc = x + (m0 + xrow) * 1024 + xc4;  // second row = +32*1024
  const unsigned short* wsrc0 = Wt + ((0 * 512 + tid) >> 3) * 1024 + (tid & 7) * 8;
  const unsigned short* wsrc1 = Wt + ((1 * 512 + tid) >> 3) * 1024 + (tid & 7) * 8;
  const unsigned short* wsrc2 = Wt + ((2 * 512 + tid) >> 3) * 1024 + (tid & 7) * 8;

  f32x4 acc[2][3] = {};
  const int arow = wg * 32 + lr;  // subtile 0 row; subtile 1 = +16

#define WSTAGE(k0, buf)                                                      \
  do {                                                                       \
    gld_lds16(wsrc0 + (k0), (char*)(&ws[buf][0]) + w * 1024);                \
    gld_lds16(wsrc1 + (k0), (char*)(&ws[buf][0]) + 8192 + w * 1024);         \
    gld_lds16(wsrc2 + (k0), (char*)(&ws[buf][0]) + 16384 + w * 1024);        \
  } while (0)
#define XWRITE(v0, v1, buf)                                                  \
  do {                                                                       \
    bf16x4 t0, t1;                                                           \
    t0[0] = (__bf16)(v0).x; t0[1] = (__bf16)(v0).y;                          \
    t0[2] = (__bf16)(v0).z; t0[3] = (__bf16)(v0).w;                          \
    t1[0] = (__bf16)(v1).x; t1[1] = (__bf16)(v1).y;                          \
    t1[2] = (__bf16)(v1).z; t1[3] = (__bf16)(v1).w;                          \
    *reinterpret_cast<bf16x4*>(&xs[buf][xrow][xc4]) = t0;                    \
    *reinterpret_cast<bf16x4*>(&xs[buf][xrow + 32][xc4]) = t1;               \
  } while (0)

  // prologue: tile 0 staged; x pair for t=1 issued and left in flight
  float4 xrA0 = *reinterpret_cast<const float4*>(xsrc);
  float4 xrA1 = *reinterpret_cast<const float4*>(xsrc + 32 * 1024);
  WSTAGE(0, 0);
  XWRITE(xrA0, xrA1, 0);  // compiler auto-waits the x(0) pair
  xrA0 = *reinterpret_cast<const float4*>(xsrc + 64);
  xrA1 = *reinterpret_cast<const float4*>(xsrc + 32 * 1024 + 64);
  asm volatile("s_waitcnt vmcnt(2) lgkmcnt(0)" ::: "memory");  // W(0) done
  __builtin_amdgcn_s_barrier();

#pragma unroll
  for (int t = 0; t < 16; ++t) {
    const int cur = t & 1;
    if (t < 15) WSTAGE((t + 1) * 64, cur ^ 1);  // 3 gld_lds (oldest vmem)
    __builtin_amdgcn_sched_barrier(0);
    float4 xrB0 = {}, xrB1 = {};
    if (t < 14) {
      xrB0 = *reinterpret_cast<const float4*>(xsrc + (t + 2) * 64);  // newest
      xrB1 = *reinterpret_cast<const float4*>(xsrc + 32 * 1024 + (t + 2) * 64);
    }
    __builtin_amdgcn_sched_barrier(0);

    // A fragments: two 16-row subtiles
    bf16x8 a[2][2];
#pragma unroll
    for (int sub = 0; sub < 2; ++sub)
#pragma unroll
      for (int kh = 0; kh < 2; ++kh)
        a[sub][kh] = *reinterpret_cast<const bf16x8*>(
            &xs[cur][arow + sub * 16][kh * 32 + lg * 8]);
    // B fragments read once, used for both subtiles
#pragma unroll
    for (int cf = 0; cf < 3; ++cf) {
      const int n = wc * 48 + cf * 16 + lr;
      const unsigned short* wr = &ws[cur][n * 64];
#pragma unroll
      for (int kh = 0; kh < 2; ++kh) {
        const int sc = (kh * 4 + lg) ^ (n & 7);
        const bf16x8 bv8 = *reinterpret_cast<const bf16x8*>(wr + sc * 8);
        acc[0][cf] = MFMA16(a[0][kh], bv8, acc[0][cf]);
        acc[1][cf] = MFMA16(a[1][kh], bv8, acc[1][cf]);
      }
    }
    if (t < 15) {
      XWRITE(xrA0, xrA1, cur ^ 1);  // xrA pair loaded 1 step ago (landed)
      if (t < 14)
        asm volatile("s_waitcnt vmcnt(2) lgkmcnt(0)" ::: "memory");  // keep xrB
      else
        asm volatile("s_waitcnt vmcnt(0) lgkmcnt(0)" ::: "memory");
      __builtin_amdgcn_s_barrier();
      xrA0 = xrB0;
      xrA1 = xrB1;
    }
  }
#undef WSTAGE
#undef XWRITE

  const int b = m0 >> 11;
#pragma unroll
  for (int sub = 0; sub < 2; ++sub) {
    const int mb = m0 + wg * 32 + sub * 16 + lg * 4;
#pragma unroll
    for (int cf = 0; cf < 3; ++cf) {
      const int n = wc * 48 + cf * 16 + lr;
      if (n < 64) {
        const float bias = bq[n] * SCALE_Q;
#pragma unroll
        for (int i = 0; i < 4; ++i)
          Q[(mb + i) * 64 + n] = f2bf(acc[sub][cf][i] + bias);
      } else if (n < 128) {
        const int nn = n - 64;
        const float bias = bk[nn];
#pragma unroll
        for (int i = 0; i < 4; ++i)
          K[(mb + i) * 64 + nn] = f2bf(acc[sub][cf][i] + bias);
      } else {
        const int d = n - 128;
        const float bias = bv[d];
        ushort4 o;
        o.x = f2bf(acc[sub][cf][0] + bias);
        o.y = f2bf(acc[sub][cf][1] + bias);
        o.z = f2bf(acc[sub][cf][2] + bias);
        o.w = f2bf(acc[sub][cf][3] + bias);
        const int sl = (m0 & 2047) + wg * 32 + sub * 16 + lg * 4;
        *reinterpret_cast<ushort4*>(&Vt[((b * 64 + d) << 11) + sl]) = o;
      }
    }
  }
}

// ---------------------------------------------------------------------------
// Kernel 2: flash attention partial over a 512-key chunk (r14 version --
// best measured). 4 waves x 32 q-rows, BKV=64, 8 iters; swapped QK^T via
// mfma32; register softmax (log2 domain); cvt_pk+permlane32_swap P->A;
// uniform mask-skip. grid (16,8,4) = 512 blocks.
// ---------------------------------------------------------------------------
__global__ __launch_bounds__(256) void attn_kernel(
    const unsigned short* __restrict__ Q, const unsigned short* __restrict__ K,
    const unsigned short* __restrict__ Vt, const float* __restrict__ mAddG,
    const int* __restrict__ maskI, unsigned short* __restrict__ Opb,
    float* __restrict__ mp, float* __restrict__ lp) {
  __shared__ __align__(16) unsigned short ks[64][72];  // K tile [key][d]
  __shared__ __align__(16) unsigned short vs[64][72];  // V^T tile [d][key]
  __shared__ int fl[4];

  const int qt = blockIdx.x, b = blockIdx.y, c = blockIdx.z;
  const int tid = threadIdx.x;
  const int w = tid >> 6, lane = tid & 63;
  const int l31 = lane & 31, h = lane >> 5;
  const int bh = b * 2048;
  const int qb = qt * 128 + w * 32;              // this wave's q base (local)
  const int sr = tid >> 3, scc = (tid & 7) * 8;  // staging row/col

  // uniform hasMask flag for this 512-key chunk (2 mask ints per thread)
  {
    const int mz = ((maskI[bh + c * 512 + tid] == 0) ? 1 : 0) |
                   ((maskI[bh + c * 512 + 256 + tid] == 0) ? 1 : 0);
    const unsigned long long bal = __ballot(mz);
    if (lane == 0) fl[w] = (bal != 0ull) ? 1 : 0;
  }
  __syncthreads();
  const bool hasMask = (fl[0] | fl[1] | fl[2] | fl[3]) != 0;

  // Q fragments (B-operand of swapped QK^T)
  bf16x8 qf[4];
#pragma unroll
  for (int dt = 0; dt < 4; ++dt)
    qf[dt] = *reinterpret_cast<const bf16x8*>(
        &Q[(bh + qb + l31) * 64 + dt * 16 + h * 8]);

  // tile-0 K/V loads into registers
  uint4 rk0, rk1, rv0, rv1;
  {
    const int kv0 = c * 512;
    rk0 = *reinterpret_cast<const uint4*>(&K[(bh + kv0 + sr) * 64 + scc]);
    rk1 = *reinterpret_cast<const uint4*>(&K[(bh + kv0 + 32 + sr) * 64 + scc]);
    rv0 = *reinterpret_cast<const uint4*>(&Vt[(b * 64 + sr) * 2048 + kv0 + scc]);
    rv1 = *reinterpret_cast<const uint4*>(&Vt[(b * 64 + 32 + sr) * 2048 + kv0 + scc]);
  }

  f32x16 oacc[2] = {};  // O[q(reg)][d = nf*32 + l31]
  float m_s = -__builtin_inff(), l_s = 0.0f;

  for (int it = 0; it < 8; ++it) {
    const int kv0 = c * 512 + it * 64;
    __builtin_amdgcn_s_barrier();  // previous tile's LDS reads complete

    // write tile `it` regs -> LDS (compiler inserts the needed vmcnt wait)
    *reinterpret_cast<uint4*>(&ks[sr][scc]) = rk0;
    *reinterpret_cast<uint4*>(&ks[32 + sr][scc]) = rk1;
    *reinterpret_cast<uint4*>(&vs[sr][scc]) = rv0;
    *reinterpret_cast<uint4*>(&vs[32 + sr][scc]) = rv1;

    // issue tile it+1 loads; they fly across the barrier + compute below
    if (it < 7) {
      const int kvn = kv0 + 64;
      rk0 = *reinterpret_cast<const uint4*>(&K[(bh + kvn + sr) * 64 + scc]);
      rk1 = *reinterpret_cast<const uint4*>(&K[(bh + kvn + 32 + sr) * 64 + scc]);
      rv0 = *reinterpret_cast<const uint4*>(&Vt[(b * 64 + sr) * 2048 + kvn + scc]);
      rv1 = *reinterpret_cast<const uint4*>(&Vt[(b * 64 + 32 + sr) * 2048 + kvn + scc]);
    }

    asm volatile("s_waitcnt lgkmcnt(0)" ::: "memory");  // my ds_writes done
    __builtin_amdgcn_s_barrier();                       // everyone's done

    // ---- swapped QK^T: st regs r = S2[key=kv0+kt*32+(r&3)+8(r>>2)+4h][q]
    f32x16 st0 = {}, st1 = {};
    __builtin_amdgcn_s_setprio(1);
#pragma unroll
    for (int dt = 0; dt < 4; ++dt) {
      const bf16x8 kf0 = *reinterpret_cast<const bf16x8*>(&ks[l31][dt * 16 + h * 8]);
      st0 = MFMA32(kf0, qf[dt], st0);
    }
#pragma unroll
    for (int dt = 0; dt < 4; ++dt) {
      const bf16x8 kf1 = *reinterpret_cast<const bf16x8*>(&ks[32 + l31][dt * 16 + h * 8]);
      st1 = MFMA32(kf1, qf[dt], st1);
    }
    __builtin_amdgcn_s_setprio(0);

    if (hasMask) {  // uniform branch; skipped entirely for all-ones mask
#pragma unroll
      for (int rb = 0; rb < 4; ++rb) {
        const f32x4 md0 =
            *reinterpret_cast<const f32x4*>(&mAddG[bh + kv0 + rb * 8 + 4 * h]);
        const f32x4 md1 = *reinterpret_cast<const f32x4*>(
            &mAddG[bh + kv0 + 32 + rb * 8 + 4 * h]);
#pragma unroll
        for (int j = 0; j < 4; ++j) {
          st0[rb * 4 + j] += md0[j];
          st1[rb * 4 + j] += md1[j];
        }
      }
    }

    // ---- softmax (log2 domain): in-lane tree + one shfl_xor(32)
    float pm = st0[0];
#pragma unroll
    for (int r = 1; r < 16; ++r) pm = fmaxf(pm, st0[r]);
#pragma unroll
    for (int r = 0; r < 16; ++r) pm = fmaxf(pm, st1[r]);
    pm = fmaxf(pm, __shfl_xor(pm, 32));
    const float nm = fmaxf(m_s, pm);
    if (!__all(nm <= m_s + DEFER_TH)) {  // T13 defer-max
      const float scn = fexp2(m_s - nm);
      m_s = nm;
      l_s *= scn;
#pragma unroll
      for (int r = 0; r < 16; ++r) {
        const float scr = __shfl(scn, (r & 3) + 8 * (r >> 2) + 4 * h);
        oacc[0][r] *= scr;
        oacc[1][r] *= scr;
      }
    }
    const float mexp = (m_s == -__builtin_inff()) ? 0.0f : m_s;
    float rs = 0.0f;
#pragma unroll
    for (int r = 0; r < 16; ++r) {
      const float p0 = fexp2(st0[r] - mexp);
      st0[r] = p0;
      rs += p0;
      const float p1 = fexp2(st1[r] - mexp);
      st1[r] = p1;
      rs += p1;
    }
    rs += __shfl_xor(rs, 32);
    l_s += rs;

    // ---- P -> PV A-fragments in registers (cvt_pk + permlane32_swap)
    unsigned int paw[4][4];
#pragma unroll
    for (int kt16 = 0; kt16 < 4; ++kt16) {
      const int lo = kt16 & 1;
      unsigned int X0, X1, Y0, Y1;
      if (kt16 < 2) {
        X0 = cvtpk(st0[lo * 8 + 0], st0[lo * 8 + 1]);
        Y0 = cvtpk(st0[lo * 8 + 2], st0[lo * 8 + 3]);
        X1 = cvtpk(st0[lo * 8 + 4], st0[lo * 8 + 5]);
        Y1 = cvtpk(st0[lo * 8 + 6], st0[lo * 8 + 7]);
      } else {
        X0 = cvtpk(st1[lo * 8 + 0], st1[lo * 8 + 1]);
        Y0 = cvtpk(st1[lo * 8 + 2], st1[lo * 8 + 3]);
        X1 = cvtpk(st1[lo * 8 + 4], st1[lo * 8 + 5]);
        Y1 = cvtpk(st1[lo * 8 + 6], st1[lo * 8 + 7]);
      }
      plswap(X0, X1);
      plswap(Y0, Y1);
      paw[kt16][0] = X0;
      paw[kt16][1] = Y0;
      paw[kt16][2] = X1;
      paw[kt16][3] = Y1;
    }

    // ---- PV: A = pa (regs), B = V^T from LDS
    __builtin_amdgcn_s_setprio(1);
#pragma unroll
    for (int nf = 0; nf < 2; ++nf)
#pragma unroll
      for (int kt16 = 0; kt16 < 4; ++kt16) {
        const bf16x8 vb = *reinterpret_cast<const bf16x8*>(
            &vs[nf * 32 + l31][kt16 * 16 + h * 8]);
        const bf16x8 pa = *reinterpret_cast<const bf16x8*>(&paw[kt16][0]);
        oacc[nf] = MFMA32(pa, vb, oacc[nf]);
      }
    __builtin_amdgcn_s_setprio(0);
  }

  // epilogue: NORMALIZED bf16 partial O + (m, l)
  const float inv_s = (l_s > 0.0f) ? 1.0f / l_s : 0.0f;
#pragma unroll
  for (int r = 0; r < 16; ++r) {
    const int qoff = (r & 3) + 8 * (r >> 2) + 4 * h;
    const float invr = __shfl(inv_s, qoff);
    const int row = bh + qb + qoff;
    Opb[(c * 16384 + row) * 64 + l31] = f2bf(oacc[0][r] * invr);
    Opb[(c * 16384 + row) * 64 + 32 + l31] = f2bf(oacc[1][r] * invr);
  }
  if (h == 0) {
    mp[c * 16384 + bh + qb + l31] = m_s;
    lp[c * 16384 + bh + qb + l31] = l_s;
  }
}

// ---------------------------------------------------------------------------
// Kernel 3: merge 4 normalized bf16 partials (log2-domain m):
//   out = sum_c exp2(m_c-M)*l_c*O_c / sum_c exp2(m_c-M)*l_c
// ---------------------------------------------------------------------------
__global__ __launch_bounds__(256) void merge_kernel(
    const unsigned short* __restrict__ Opb, const float* __restrict__ mp,
    const float* __restrict__ lp, float* __restrict__ out) {
  const int t = blockIdx.x * 256 + threadIdx.x;  // 0..262143
  const int row = t >> 4;                        // b*2048 + q
  const int cc = (t & 15) * 4;
  float mv[4], lv[4];
#pragma unroll
  for (int c = 0; c < 4; ++c) {
    mv[c] = mp[c * 16384 + row];
    lv[c] = lp[c * 16384 + row];
  }
  float M = fmaxf(fmaxf(mv[0], mv[1]), fmaxf(mv[2], mv[3]));
  float L = 0.0f;
  f32x4 o = {};
#pragma unroll
  for (int c = 0; c < 4; ++c) {
    const float wc = __builtin_amdgcn_exp2f(mv[c] - M) * lv[c];
    L += wc;
    const ushort4 u = *reinterpret_cast<const ushort4*>(
        &Opb[(c * 16384 + row) * 64 + cc]);
    f32x4 oc;
    oc[0] = bf2f(u.x); oc[1] = bf2f(u.y); oc[2] = bf2f(u.z); oc[3] = bf2f(u.w);
    o += oc * wc;
  }
  const float inv = 1.0f / L;
  *reinterpret_cast<f32x4*>(&out[row * 64 + cc]) = o * inv;
}

// ---------------------------------------------------------------------------
extern "C" void kernel_launch(void* const* d_in, const int* in_sizes, int n_in,
                              void* d_out, int out_size, void* d_ws, size_t ws_size,
                              hipStream_t stream) {
  const float* x  = (const float*)d_in[0];
  const int* mask = (const int*)d_in[1];
  const float* Wq = (const float*)d_in[2];
  const float* bq = (const float*)d_in[3];
  const float* Wk = (const float*)d_in[4];
  const float* bk = (const float*)d_in[5];
  const float* Wv = (const float*)d_in[6];
  const float* bv = (const float*)d_in[7];
  float* out = (float*)d_out;

  unsigned short* Wt = (unsigned short*)d_ws;   // [192][1024] swizzled bf16
  unsigned short* Qw = Wt + 192 * 1024;         // [8][2048][64]
  unsigned short* Kw = Qw + 16384 * 64;         // [8][2048][64]
  unsigned short* Vt = Kw + 16384 * 64;         // [8][64][2048]
  unsigned short* Opb = Vt + 16384 * 64;        // [4][16384][64] bf16
  float* mAddG = (float*)(Opb + 4 * 16384 * 64);// [8*2048]
  float* mp = mAddG + 16384;                    // [4][16384]
  float* lp = mp + 4 * 16384;                   // [4][16384]

  hipLaunchKernelGGL(wt_kernel, dim3(320), dim3(128), 0, stream,
                     Wq, Wk, Wv, Wt, mask, mAddG);
  hipLaunchKernelGGL(qkv_kernel, dim3(256), dim3(512), 0, stream,
                     x, Wt, bq, bk, bv, Qw, Kw, Vt);
  hipLaunchKernelGGL(attn_kernel, dim3(16, 8, 4), dim3(256), 0, stream,
                     Qw, Kw, Vt, mAddG, mask, Opb, mp, lp);
  hipLaunchKernelGGL(merge_kernel, dim3(1024), dim3(256), 0, stream,
                     Opb, mp, lp, out);
}

// Round 16
// 47.279 us; speedup vs baseline: 1.0651x; 1.0651x over previous
//
#include <hip/hip_runtime.h>

typedef __bf16 bf16x8 __attribute__((ext_vector_type(8)));
typedef __bf16 bf16x4 __attribute__((ext_vector_type(4)));
typedef float f32x4 __attribute__((ext_vector_type(4)));
typedef float f32x16 __attribute__((ext_vector_type(16)));
typedef unsigned short u16x8 __attribute__((ext_vector_type(8)));

#define MFMA16(a, b, c) __builtin_amdgcn_mfma_f32_16x16x32_bf16((a), (b), (c), 0, 0, 0)
#define MFMA32(a, b, c) __builtin_amdgcn_mfma_f32_32x32x16_bf16((a), (b), (c), 0, 0, 0)

#define SCALE_Q 0.180336880f  // 0.125 * log2(e): scores land in log2 domain
#define DEFER_TH 11.5415603f  // 8 * log2(e)

// fast exp2 on gfx950 (v_exp_f32 is base-2 natively)
static __device__ __forceinline__ float fexp2(float x) {
  return __builtin_amdgcn_exp2f(x);
}

// fp32 -> bf16 bits, round-to-nearest-even
static __device__ __forceinline__ unsigned short f2bf(float f) {
  unsigned int u = __float_as_uint(f);
  u += 0x7fffu + ((u >> 16) & 1u);
  return (unsigned short)(u >> 16);
}
static __device__ __forceinline__ float bf2f(unsigned short s) {
  return __uint_as_float((unsigned int)s << 16);
}
// packed f32x2 -> bf16x2 (RNE), single VALU op
static __device__ __forceinline__ unsigned int cvtpk(float lo, float hi) {
  unsigned int r;
  asm("v_cvt_pk_bf16_f32 %0, %1, %2" : "=v"(r) : "v"(lo), "v"(hi));
  return r;
}
static __device__ __forceinline__ void plswap(unsigned int& a, unsigned int& b) {
  asm("v_permlane32_swap_b32 %0, %1" : "+v"(a), "+v"(b));
}

// async global->LDS, 16B per lane
static __device__ __forceinline__ void gld_lds16(const void* g, void* l) {
  __builtin_amdgcn_global_load_lds(
      (const __attribute__((address_space(1))) unsigned int*)(g),
      (__attribute__((address_space(3))) unsigned int*)(l), 16, 0, 0);
}

// ---------------------------------------------------------------------------
// Kernel 0: blocks 0..191: W [1024][64] fp32 x3 -> Wt bf16 [192][1024],
// pre-swizzled in 16B chunks (chunk j stored at j^(n&7)); Wq part * SCALE_Q
// (log2-domain scores). Blocks 192..319: mask -> mAddG float (0 / -inf).
// ---------------------------------------------------------------------------
__global__ __launch_bounds__(128) void wt_kernel(
    const float* __restrict__ Wq, const float* __restrict__ Wk,
    const float* __restrict__ Wv, unsigned short* __restrict__ Wt,
    const int* __restrict__ mask, float* __restrict__ mAddG) {
  const int bid = blockIdx.x;
  if (bid >= 192) {
    const int idx = (bid - 192) * 128 + threadIdx.x;  // 0..16383
    mAddG[idx] = mask[idx] ? 0.0f : -__builtin_inff();
    return;
  }
  const int n = bid;           // 0..191 (qkv output col)
  const int jl = threadIdx.x;  // logical 8-elem chunk of K
  const float* W;
  int col;
  float scale;
  if (n < 64)       { W = Wq; col = n;       scale = SCALE_Q; }
  else if (n < 128) { W = Wk; col = n - 64;  scale = 1.0f; }
  else              { W = Wv; col = n - 128; scale = 1.0f; }
  const int js = (jl & ~7) | ((jl & 7) ^ (n & 7));  // swizzled chunk position
  u16x8 o;
#pragma unroll
  for (int e = 0; e < 8; ++e) o[e] = f2bf(W[(jl * 8 + e) * 64 + col] * scale);
  *reinterpret_cast<u16x8*>(&Wt[n * 1024 + js * 8]) = o;
}

// ---------------------------------------------------------------------------
// Kernel 1: QKV projection GEMM (r9/r14 version -- best measured, ~25us).
// Tile 32x192, grid 512, 512 threads (8 waves). Double-buffered LDS; W via
// global_load_lds; x reg loads 2-deep with raw s_barrier + counted vmcnt(1).
// ---------------------------------------------------------------------------
__global__ __launch_bounds__(512, 4) void qkv_kernel(
    const float* __restrict__ x, const unsigned short* __restrict__ Wt,
    const float* __restrict__ bq, const float* __restrict__ bk,
    const float* __restrict__ bv, unsigned short* __restrict__ Q,
    unsigned short* __restrict__ K, unsigned short* __restrict__ Vt) {
  __shared__ __align__(16) unsigned short xs[2][32][72];    // padded
  __shared__ __align__(16) unsigned short ws[2][192 * 64];  // swizzled content
  const int tid = threadIdx.x;
  const int w = tid >> 6, lane = tid & 63;
  const int lr = lane & 15, lg = lane >> 4;
  const int wg = w >> 2, wc = w & 3;
  const int m0 = blockIdx.x * 32;

  const int xrow = tid >> 4, xc4 = (tid & 15) * 4;
  const float* xsrc = x + (m0 + xrow) * 1024 + xc4;
  const unsigned short* wsrc0 = Wt + ((0 * 512 + tid) >> 3) * 1024 + (tid & 7) * 8;
  const unsigned short* wsrc1 = Wt + ((1 * 512 + tid) >> 3) * 1024 + (tid & 7) * 8;
  const unsigned short* wsrc2 = Wt + ((2 * 512 + tid) >> 3) * 1024 + (tid & 7) * 8;

  f32x4 acc[3] = {};
  const int arow = wg * 16 + lr;

#define WSTAGE(k0, buf)                                                      \
  do {                                                                       \
    gld_lds16(wsrc0 + (k0), (char*)(&ws[buf][0]) + w * 1024);                \
    gld_lds16(wsrc1 + (k0), (char*)(&ws[buf][0]) + 8192 + w * 1024);         \
    gld_lds16(wsrc2 + (k0), (char*)(&ws[buf][0]) + 16384 + w * 1024);        \
  } while (0)
#define XWRITE(v, buf)                                                       \
  do {                                                                       \
    bf16x4 xb;                                                               \
    xb[0] = (__bf16)(v).x; xb[1] = (__bf16)(v).y;                            \
    xb[2] = (__bf16)(v).z; xb[3] = (__bf16)(v).w;                            \
    *reinterpret_cast<bf16x4*>(&xs[buf][xrow][xc4]) = xb;                    \
  } while (0)

  // prologue: tile 0 staged; x for t=1 issued and left in flight
  float4 xrA = *reinterpret_cast<const float4*>(xsrc);
  WSTAGE(0, 0);
  XWRITE(xrA, 0);  // compiler auto-waits xrA's vmcnt
  xrA = *reinterpret_cast<const float4*>(xsrc + 64);
  asm volatile("s_waitcnt vmcnt(1) lgkmcnt(0)" ::: "memory");  // W(0) done
  __builtin_amdgcn_s_barrier();

#pragma unroll
  for (int t = 0; t < 16; ++t) {
    const int cur = t & 1;
    if (t < 15) WSTAGE((t + 1) * 64, cur ^ 1);  // 3 gld_lds (oldest vmem)
    __builtin_amdgcn_sched_barrier(0);
    float4 xrB = {};
    if (t < 14)
      xrB = *reinterpret_cast<const float4*>(xsrc + (t + 2) * 64);  // newest
    __builtin_amdgcn_sched_barrier(0);

    bf16x8 a[2];
#pragma unroll
    for (int kh = 0; kh < 2; ++kh)
      a[kh] = *reinterpret_cast<const bf16x8*>(&xs[cur][arow][kh * 32 + lg * 8]);
#pragma unroll
    for (int cf = 0; cf < 3; ++cf) {
      const int n = wc * 48 + cf * 16 + lr;
      const unsigned short* wr = &ws[cur][n * 64];
#pragma unroll
      for (int kh = 0; kh < 2; ++kh) {
        const int sc = (kh * 4 + lg) ^ (n & 7);
        bf16x8 bv8 = *reinterpret_cast<const bf16x8*>(wr + sc * 8);
        acc[cf] = MFMA16(a[kh], bv8, acc[cf]);
      }
    }
    if (t < 15) {
      XWRITE(xrA, cur ^ 1);  // xrA loaded 1 step ago (auto-waited, landed)
      if (t < 14)
        asm volatile("s_waitcnt vmcnt(1) lgkmcnt(0)" ::: "memory");  // keep xrB
      else
        asm volatile("s_waitcnt vmcnt(0) lgkmcnt(0)" ::: "memory");
      __builtin_amdgcn_s_barrier();
      xrA = xrB;
    }
  }
#undef WSTAGE
#undef XWRITE

  const int mb = m0 + wg * 16 + lg * 4;
  const int b = m0 >> 11;
#pragma unroll
  for (int cf = 0; cf < 3; ++cf) {
    const int n = wc * 48 + cf * 16 + lr;
    if (n < 64) {
      const float bias = bq[n] * SCALE_Q;
#pragma unroll
      for (int i = 0; i < 4; ++i) Q[(mb + i) * 64 + n] = f2bf(acc[cf][i] + bias);
    } else if (n < 128) {
      const int nn = n - 64;
      const float bias = bk[nn];
#pragma unroll
      for (int i = 0; i < 4; ++i) K[(mb + i) * 64 + nn] = f2bf(acc[cf][i] + bias);
    } else {
      const int d = n - 128;
      const float bias = bv[d];
      ushort4 o;
      o.x = f2bf(acc[cf][0] + bias);
      o.y = f2bf(acc[cf][1] + bias);
      o.z = f2bf(acc[cf][2] + bias);
      o.w = f2bf(acc[cf][3] + bias);
      const int sl = (m0 & 2047) + wg * 16 + lg * 4;
      *reinterpret_cast<ushort4*>(&Vt[((b * 64 + d) << 11) + sl]) = o;
    }
  }
}

// ---------------------------------------------------------------------------
// Kernel 2: flash attention partial over a 512-key chunk -- r14 structure
// with DOUBLE-BUFFERED K/V LDS and ONE barrier per iter. Iter t: write tile
// t+1 regs -> buf^1 (overlaps compute on buf), issue tile t+2 loads, compute,
// lgkmcnt(0)+barrier. Safety: each wave's lgkmcnt(0) before the barrier
// drains its ds_reads of buf[t&1], so iter t+1's write of that buffer cannot
// race a stale reader. LDS 73.7 KB -> 2 blocks/CU (grid 512 = 2/CU anyway).
// ---------------------------------------------------------------------------
__global__ __launch_bounds__(256) void attn_kernel(
    const unsigned short* __restrict__ Q, const unsigned short* __restrict__ K,
    const unsigned short* __restrict__ Vt, const float* __restrict__ mAddG,
    const int* __restrict__ maskI, unsigned short* __restrict__ Opb,
    float* __restrict__ mp, float* __restrict__ lp) {
  __shared__ __align__(16) unsigned short ks[2][64][72];  // K tiles [buf][key][d]
  __shared__ __align__(16) unsigned short vs[2][64][72];  // V^T tiles [buf][d][key]
  __shared__ int fl[4];

  const int qt = blockIdx.x, b = blockIdx.y, c = blockIdx.z;
  const int tid = threadIdx.x;
  const int w = tid >> 6, lane = tid & 63;
  const int l31 = lane & 31, h = lane >> 5;
  const int bh = b * 2048;
  const int qb = qt * 128 + w * 32;              // this wave's q base (local)
  const int sr = tid >> 3, scc = (tid & 7) * 8;  // staging row/col

  // uniform hasMask flag for this 512-key chunk (2 mask ints per thread)
  {
    const int mz = ((maskI[bh + c * 512 + tid] == 0) ? 1 : 0) |
                   ((maskI[bh + c * 512 + 256 + tid] == 0) ? 1 : 0);
    const unsigned long long bal = __ballot(mz);
    if (lane == 0) fl[w] = (bal != 0ull) ? 1 : 0;
  }
  __syncthreads();
  const bool hasMask = (fl[0] | fl[1] | fl[2] | fl[3]) != 0;

  // Q fragments (B-operand of swapped QK^T)
  bf16x8 qf[4];
#pragma unroll
  for (int dt = 0; dt < 4; ++dt)
    qf[dt] = *reinterpret_cast<const bf16x8*>(
        &Q[(bh + qb + l31) * 64 + dt * 16 + h * 8]);

  // tile-0 regs -> buf0; then tile-1 regs left in flight
  uint4 rk0, rk1, rv0, rv1;
  {
    const int kv0 = c * 512;
    rk0 = *reinterpret_cast<const uint4*>(&K[(bh + kv0 + sr) * 64 + scc]);
    rk1 = *reinterpret_cast<const uint4*>(&K[(bh + kv0 + 32 + sr) * 64 + scc]);
    rv0 = *reinterpret_cast<const uint4*>(&Vt[(b * 64 + sr) * 2048 + kv0 + scc]);
    rv1 = *reinterpret_cast<const uint4*>(&Vt[(b * 64 + 32 + sr) * 2048 + kv0 + scc]);
  }
  *reinterpret_cast<uint4*>(&ks[0][sr][scc]) = rk0;
  *reinterpret_cast<uint4*>(&ks[0][32 + sr][scc]) = rk1;
  *reinterpret_cast<uint4*>(&vs[0][sr][scc]) = rv0;
  *reinterpret_cast<uint4*>(&vs[0][32 + sr][scc]) = rv1;
  {
    const int kvn = c * 512 + 64;
    rk0 = *reinterpret_cast<const uint4*>(&K[(bh + kvn + sr) * 64 + scc]);
    rk1 = *reinterpret_cast<const uint4*>(&K[(bh + kvn + 32 + sr) * 64 + scc]);
    rv0 = *reinterpret_cast<const uint4*>(&Vt[(b * 64 + sr) * 2048 + kvn + scc]);
    rv1 = *reinterpret_cast<const uint4*>(&Vt[(b * 64 + 32 + sr) * 2048 + kvn + scc]);
  }
  asm volatile("s_waitcnt lgkmcnt(0)" ::: "memory");  // buf0 writes done
  __builtin_amdgcn_s_barrier();

  f32x16 oacc[2] = {};  // O[q(reg)][d = nf*32 + l31]
  float m_s = -__builtin_inff(), l_s = 0.0f;

  for (int it = 0; it < 8; ++it) {
    const int kv0 = c * 512 + it * 64;
    const int cur = it & 1;

    // write tile it+1 (in regs, landed) into the other buffer; overlaps
    // this iter's compute. Then issue tile it+2 loads (fly across barrier).
    if (it < 7) {
      *reinterpret_cast<uint4*>(&ks[cur ^ 1][sr][scc]) = rk0;
      *reinterpret_cast<uint4*>(&ks[cur ^ 1][32 + sr][scc]) = rk1;
      *reinterpret_cast<uint4*>(&vs[cur ^ 1][sr][scc]) = rv0;
      *reinterpret_cast<uint4*>(&vs[cur ^ 1][32 + sr][scc]) = rv1;
      if (it < 6) {
        const int kvn = kv0 + 128;
        rk0 = *reinterpret_cast<const uint4*>(&K[(bh + kvn + sr) * 64 + scc]);
        rk1 = *reinterpret_cast<const uint4*>(&K[(bh + kvn + 32 + sr) * 64 + scc]);
        rv0 = *reinterpret_cast<const uint4*>(&Vt[(b * 64 + sr) * 2048 + kvn + scc]);
        rv1 = *reinterpret_cast<const uint4*>(&Vt[(b * 64 + 32 + sr) * 2048 + kvn + scc]);
      }
    }

    // ---- swapped QK^T: st regs r = S2[key=kv0+kt*32+(r&3)+8(r>>2)+4h][q]
    f32x16 st0 = {}, st1 = {};
    __builtin_amdgcn_s_setprio(1);
#pragma unroll
    for (int dt = 0; dt < 4; ++dt) {
      const bf16x8 kf0 =
          *reinterpret_cast<const bf16x8*>(&ks[cur][l31][dt * 16 + h * 8]);
      st0 = MFMA32(kf0, qf[dt], st0);
    }
#pragma unroll
    for (int dt = 0; dt < 4; ++dt) {
      const bf16x8 kf1 =
          *reinterpret_cast<const bf16x8*>(&ks[cur][32 + l31][dt * 16 + h * 8]);
      st1 = MFMA32(kf1, qf[dt], st1);
    }
    __builtin_amdgcn_s_setprio(0);

    if (hasMask) {  // uniform branch; skipped entirely for all-ones mask
#pragma unroll
      for (int rb = 0; rb < 4; ++rb) {
        const f32x4 md0 =
            *reinterpret_cast<const f32x4*>(&mAddG[bh + kv0 + rb * 8 + 4 * h]);
        const f32x4 md1 = *reinterpret_cast<const f32x4*>(
            &mAddG[bh + kv0 + 32 + rb * 8 + 4 * h]);
#pragma unroll
        for (int j = 0; j < 4; ++j) {
          st0[rb * 4 + j] += md0[j];
          st1[rb * 4 + j] += md1[j];
        }
      }
    }

    // ---- softmax (log2 domain): in-lane tree + one shfl_xor(32)
    float pm = st0[0];
#pragma unroll
    for (int r = 1; r < 16; ++r) pm = fmaxf(pm, st0[r]);
#pragma unroll
    for (int r = 0; r < 16; ++r) pm = fmaxf(pm, st1[r]);
    pm = fmaxf(pm, __shfl_xor(pm, 32));
    const float nm = fmaxf(m_s, pm);
    if (!__all(nm <= m_s + DEFER_TH)) {  // T13 defer-max
      const float scn = fexp2(m_s - nm);
      m_s = nm;
      l_s *= scn;
#pragma unroll
      for (int r = 0; r < 16; ++r) {
        const float scr = __shfl(scn, (r & 3) + 8 * (r >> 2) + 4 * h);
        oacc[0][r] *= scr;
        oacc[1][r] *= scr;
      }
    }
    const float mexp = (m_s == -__builtin_inff()) ? 0.0f : m_s;
    float rs = 0.0f;
#pragma unroll
    for (int r = 0; r < 16; ++r) {
      const float p0 = fexp2(st0[r] - mexp);
      st0[r] = p0;
      rs += p0;
      const float p1 = fexp2(st1[r] - mexp);
      st1[r] = p1;
      rs += p1;
    }
    rs += __shfl_xor(rs, 32);
    l_s += rs;

    // ---- P -> PV A-fragments in registers (cvt_pk + permlane32_swap)
    unsigned int paw[4][4];
#pragma unroll
    for (int kt16 = 0; kt16 < 4; ++kt16) {
      const int lo = kt16 & 1;
      unsigned int X0, X1, Y0, Y1;
      if (kt16 < 2) {
        X0 = cvtpk(st0[lo * 8 + 0], st0[lo * 8 + 1]);
        Y0 = cvtpk(st0[lo * 8 + 2], st0[lo * 8 + 3]);
        X1 = cvtpk(st0[lo * 8 + 4], st0[lo * 8 + 5]);
        Y1 = cvtpk(st0[lo * 8 + 6], st0[lo * 8 + 7]);
      } else {
        X0 = cvtpk(st1[lo * 8 + 0], st1[lo * 8 + 1]);
        Y0 = cvtpk(st1[lo * 8 + 2], st1[lo * 8 + 3]);
        X1 = cvtpk(st1[lo * 8 + 4], st1[lo * 8 + 5]);
        Y1 = cvtpk(st1[lo * 8 + 6], st1[lo * 8 + 7]);
      }
      plswap(X0, X1);
      plswap(Y0, Y1);
      paw[kt16][0] = X0;
      paw[kt16][1] = Y0;
      paw[kt16][2] = X1;
      paw[kt16][3] = Y1;
    }

    // ---- PV: A = pa (regs), B = V^T from LDS
    __builtin_amdgcn_s_setprio(1);
#pragma unroll
    for (int nf = 0; nf < 2; ++nf)
#pragma unroll
      for (int kt16 = 0; kt16 < 4; ++kt16) {
        const bf16x8 vb = *reinterpret_cast<const bf16x8*>(
            &vs[cur][nf * 32 + l31][kt16 * 16 + h * 8]);
        const bf16x8 pa = *reinterpret_cast<const bf16x8*>(&paw[kt16][0]);
        oacc[nf] = MFMA32(pa, vb, oacc[nf]);
      }
    __builtin_amdgcn_s_setprio(0);

    // one barrier per iter: my ds ops (reads of buf[cur], writes of buf^1)
    // are drained, so next iter may safely overwrite buf[cur].
    asm volatile("s_waitcnt lgkmcnt(0)" ::: "memory");
    __builtin_amdgcn_s_barrier();
  }

  // epilogue: NORMALIZED bf16 partial O + (m, l)
  const float inv_s = (l_s > 0.0f) ? 1.0f / l_s : 0.0f;
#pragma unroll
  for (int r = 0; r < 16; ++r) {
    const int qoff = (r & 3) + 8 * (r >> 2) + 4 * h;
    const float invr = __shfl(inv_s, qoff);
    const int row = bh + qb + qoff;
    Opb[(c * 16384 + row) * 64 + l31] = f2bf(oacc[0][r] * invr);
    Opb[(c * 16384 + row) * 64 + 32 + l31] = f2bf(oacc[1][r] * invr);
  }
  if (h == 0) {
    mp[c * 16384 + bh + qb + l31] = m_s;
    lp[c * 16384 + bh + qb + l31] = l_s;
  }
}

// ---------------------------------------------------------------------------
// Kernel 3: merge 4 normalized bf16 partials (log2-domain m):
//   out = sum_c exp2(m_c-M)*l_c*O_c / sum_c exp2(m_c-M)*l_c
// ---------------------------------------------------------------------------
__global__ __launch_bounds__(256) void merge_kernel(
    const unsigned short* __restrict__ Opb, const float* __restrict__ mp,
    const float* __restrict__ lp, float* __restrict__ out) {
  const int t = blockIdx.x * 256 + threadIdx.x;  // 0..262143
  const int row = t >> 4;                        // b*2048 + q
  const int cc = (t & 15) * 4;
  float mv[4], lv[4];
#pragma unroll
  for (int c = 0; c < 4; ++c) {
    mv[c] = mp[c * 16384 + row];
    lv[c] = lp[c * 16384 + row];
  }
  float M = fmaxf(fmaxf(mv[0], mv[1]), fmaxf(mv[2], mv[3]));
  float L = 0.0f;
  f32x4 o = {};
#pragma unroll
  for (int c = 0; c < 4; ++c) {
    const float wc = __builtin_amdgcn_exp2f(mv[c] - M) * lv[c];
    L += wc;
    const ushort4 u = *reinterpret_cast<const ushort4*>(
        &Opb[(c * 16384 + row) * 64 + cc]);
    f32x4 oc;
    oc[0] = bf2f(u.x); oc[1] = bf2f(u.y); oc[2] = bf2f(u.z); oc[3] = bf2f(u.w);
    o += oc * wc;
  }
  const float inv = 1.0f / L;
  *reinterpret_cast<f32x4*>(&out[row * 64 + cc]) = o * inv;
}

// ---------------------------------------------------------------------------
extern "C" void kernel_launch(void* const* d_in, const int* in_sizes, int n_in,
                              void* d_out, int out_size, void* d_ws, size_t ws_size,
                              hipStream_t stream) {
  const float* x  = (const float*)d_in[0];
  const int* mask = (const int*)d_in[1];
  const float* Wq = (const float*)d_in[2];
  const float* bq = (const float*)d_in[3];
  const float* Wk = (const float*)d_in[4];
  const float* bk = (const float*)d_in[5];
  const float* Wv = (const float*)d_in[6];
  const float* bv = (const float*)d_in[7];
  float* out = (float*)d_out;

  unsigned short* Wt = (unsigned short*)d_ws;   // [192][1024] swizzled bf16
  unsigned short* Qw = Wt + 192 * 1024;         // [8][2048][64]
  unsigned short* Kw = Qw + 16384 * 64;         // [8][2048][64]
  unsigned short* Vt = Kw + 16384 * 64;         // [8][64][2048]
  unsigned short* Opb = Vt + 16384 * 64;        // [4][16384][64] bf16
  float* mAddG = (float*)(Opb + 4 * 16384 * 64);// [8*2048]
  float* mp = mAddG + 16384;                    // [4][16384]
  float* lp = mp + 4 * 16384;                   // [4][16384]

  hipLaunchKernelGGL(wt_kernel, dim3(320), dim3(128), 0, stream,
                     Wq, Wk, Wv, Wt, mask, mAddG);
  hipLaunchKernelGGL(qkv_kernel, dim3(512), dim3(512), 0, stream,
                     x, Wt, bq, bk, bv, Qw, Kw, Vt);
  hipLaunchKernelGGL(attn_kernel, dim3(16, 8, 4), dim3(256), 0, stream,
                     Qw, Kw, Vt, mAddG, mask, Opb, mp, lp);
  hipLaunchKernelGGL(merge_kernel, dim3(1024), dim3(256), 0, stream,
                     Opb, mp, lp, out);
}